// Round 5
// baseline (1554.802 us; speedup 1.0000x reference)
//
#include <hip/hip_runtime.h>
#include <hip/hip_bf16.h>
#include <math.h>

// PSI_Full: B=8, S=4096, D=512. fp32 in/out.
// Round 5: (1) XCD-aware block swizzle in gemm_mfma — round-4's o1 GEMM was
// fetch-bound (FETCH 133 MB vs 37.5 ideal) because x-fastest dispatch puts
// each output-column on one XCD, streaming ALL of A through every per-XCD L2.
// Swizzle gives XCD c rows 8c..8c+7 x all cols (A-patch 4MB resident).
// (2) phi fp32 buffer eliminated — scan_final recomputes phi bit-identically.
// (3) scan_excl launches eliminated — prefixes summed in-kernel from raw
// partials (L2-resident).

#define BB 8
#define SS 4096
#define DD 512
#define NCH 128
#define CHS 32        // SS / NCH
#define BSL 2         // batch per slice
#define NSL 4
#define NPROJ 2560    // 5 * DD

typedef __attribute__((ext_vector_type(8))) short short8;
typedef __attribute__((ext_vector_type(4))) float f32x4;
typedef __hip_bfloat16 bf16;

__device__ inline void load_lds16(const bf16* g, bf16* l) {
  __builtin_amdgcn_global_load_lds(
      (const __attribute__((address_space(1))) void*)g,
      (__attribute__((address_space(3))) void*)l, 16, 0, 0);
}

// ---------------------------------------------------------------------------
// bf16 MFMA GEMM: C[M,N] = act(A[M,K](lda=Alda) @ WT[N,K]^T + bias[N]) (+resid)
// act: 0 none, 1 sig, 2 sig*5, 3 gelu(exact), 9 = fused-proj table by col>>9.
// Tile 128x128, BK=32, 256 threads = 4 waves (2x2), each wave 4x4 of 16x16.
// Block swizzle (gy==64 only): linear id l, XCD = l&7 -> rows 8c..8c+7, col
// = (l>>3)/8. Keeps each XCD's A working set at 8 row-tiles.
// ---------------------------------------------------------------------------
__global__ __launch_bounds__(256) void gemm_mfma(
    const bf16* __restrict__ A, int Alda,
    const bf16* __restrict__ WT,            // [N][K]
    const float* __restrict__ bias,
    const float* __restrict__ resid,        // fp32 [M][N] or null
    void* __restrict__ C, int K, int N, int act, int outBf16)
{
  __shared__ bf16 As[4096];  // [kseg 0..3][row 0..127][8]
  __shared__ bf16 Bs[4096];
  const int tid = threadIdx.x;
  int bx, by;
  if (gridDim.y == 64) {
    const int l = blockIdx.y * gridDim.x + blockIdx.x;
    const int c8 = l & 7, i = l >> 3;
    by = (c8 << 3) + (i & 7);     // row-block: XCD-contiguous band
    bx = i >> 3;                  // col-block
  } else { bx = blockIdx.x; by = blockIdx.y; }
  const int row0 = by << 7;
  const int col0 = bx << 7;
  const int lane = tid & 63;
  const int wv = tid >> 6;
  const int wr = (wv >> 1) << 6;
  const int wc = (wv & 1) << 6;
  const int q  = lane >> 4;
  const int mn = lane & 15;

  int eact = act;
  if (act == 9) { const int tbl[5] = {0, 1, 2, 3, 0}; eact = tbl[col0 >> 9]; }

  f32x4 acc[4][4];
#pragma unroll
  for (int i = 0; i < 4; ++i)
#pragma unroll
    for (int j = 0; j < 4; ++j) acc[i][j] = (f32x4){0.f, 0.f, 0.f, 0.f};

  const int srow  = tid & 127;
  const int skseg = tid >> 7;   // 0 or 1
  const bf16* Ag = A  + (size_t)(row0 + srow) * Alda + (skseg << 3);
  const bf16* Bg = WT + (size_t)(col0 + srow) * K + (skseg << 3);
  bf16* Asl = As + tid * 8;
  bf16* Bsl = Bs + tid * 8;

  for (int k0 = 0; k0 < K; k0 += 32) {
    __syncthreads();
    load_lds16(Ag + k0,      Asl);
    load_lds16(Ag + k0 + 16, Asl + 2048);
    load_lds16(Bg + k0,      Bsl);
    load_lds16(Bg + k0 + 16, Bsl + 2048);
    __syncthreads();
    const short8* Av = (const short8*)As;
    const short8* Bv = (const short8*)Bs;
    short8 af[4], bfr[4];
#pragma unroll
    for (int t = 0; t < 4; ++t) af[t]  = Av[q * 128 + wr + t * 16 + mn];
#pragma unroll
    for (int t = 0; t < 4; ++t) bfr[t] = Bv[q * 128 + wc + t * 16 + mn];
#pragma unroll
    for (int mt = 0; mt < 4; ++mt)
#pragma unroll
      for (int nt = 0; nt < 4; ++nt)
        acc[mt][nt] = __builtin_amdgcn_mfma_f32_16x16x32_bf16(
            af[mt], bfr[nt], acc[mt][nt], 0, 0, 0);
  }

  // C/D layout: col = lane&15, row = quad*4 + reg.
#pragma unroll
  for (int mt = 0; mt < 4; ++mt) {
#pragma unroll
    for (int nt = 0; nt < 4; ++nt) {
      const int gcol = col0 + wc + nt * 16 + mn;
      const float bcol = bias[gcol];
#pragma unroll
      for (int r = 0; r < 4; ++r) {
        const int grow = row0 + wr + mt * 16 + q * 4 + r;
        const size_t o = (size_t)grow * N + gcol;
        float v = acc[mt][nt][r] + bcol;
        if (eact == 1)      v = 1.f / (1.f + __expf(-v));
        else if (eact == 2) v = 5.f / (1.f + __expf(-v));
        else if (eact == 3) v = 0.5f * v * (1.f + erff(v * 0.70710678118654752f));
        if (resid) v += resid[o];
        if (outBf16) ((bf16*)C)[o] = __float2bfloat16(v);
        else         ((float*)C)[o] = v;
      }
    }
  }
}

// ---------------------------------------------------------------------------
__global__ __launch_bounds__(256) void wtrans(
    const float* __restrict__ W, bf16* __restrict__ WT, int K, int N)
{
  __shared__ float t[32][33];
  const int n0 = blockIdx.x << 5, k0 = blockIdx.y << 5;
  const int tx = threadIdx.x & 31, ty = threadIdx.x >> 5;
  for (int i = ty; i < 32; i += 8)
    t[i][tx] = W[(size_t)(k0 + i) * N + n0 + tx];
  __syncthreads();
  for (int i = ty; i < 32; i += 8)
    WT[(size_t)(n0 + i) * K + k0 + tx] = __float2bfloat16(t[tx][i]);
}

__global__ __launch_bounds__(256) void castbf(
    const float* __restrict__ in, bf16* __restrict__ o, int n)
{
  const int i = (blockIdx.x * 256 + threadIdx.x) * 4;
  if (i < n) {
    const float4 v = *(const float4*)(in + i);
    o[i]     = __float2bfloat16(v.x);
    o[i + 1] = __float2bfloat16(v.y);
    o[i + 2] = __float2bfloat16(v.z);
    o[i + 3] = __float2bfloat16(v.w);
  }
}

// bias concat: 5 segments of 512 -> bcat[2560]
__global__ void bconcat(const float* b0, const float* b1, const float* b2,
                        const float* b3, const float* b4, float* bcat)
{
  const int d = threadIdx.x;
  const float* src[5] = {b0, b1, b2, b3, b4};
  bcat[blockIdx.x * DD + d] = src[blockIdx.x][d];
}

// ---------------------------------------------------------------------------
// Scans. proj row m: [omega|gate|mag|g1|qoff] bf16, stride NPROJ.
// phi_init in phib (bf16). pA/pRIM hold RAW chunk partials; consumers sum
// their own exclusive prefix in-kernel (ascending order = bit-identical to
// the old scan_excl).
// ---------------------------------------------------------------------------
__global__ __launch_bounds__(512) void scan_partialA(
    const bf16* __restrict__ proj, const float* __restrict__ iscale,
    float* __restrict__ pA)
{
  const int b = blockIdx.x >> 7;
  const int c = blockIdx.x & (NCH - 1);
  const int d = threadIdx.x;
  const float sc = fabsf(iscale[d]);
  size_t base = (((size_t)b * SS) + (size_t)c * CHS) * NPROJ + d;
  float acc = 0.f;
  for (int s = 0; s < CHS; ++s) {
    size_t idx = base + (size_t)s * NPROJ;
    acc = fmaf(__bfloat162float(proj[idx]) * __bfloat162float(proj[idx + DD]), sc, acc);
  }
  pA[((size_t)b * NCH + c) * DD + d] = acc;
}

__global__ __launch_bounds__(512) void scan_stageB(
    const bf16* __restrict__ proj, const bf16* __restrict__ xh,
    const bf16* __restrict__ phib, const float* __restrict__ iscale,
    const float* __restrict__ pA, float* __restrict__ pRIM)
{
  const int b = blockIdx.x >> 7;
  const int c = blockIdx.x & (NCH - 1);
  const int d = threadIdx.x;
  const float sc = fabsf(iscale[d]);
  // exclusive prefix of pA over chunks < c (L2-resident, coalesced)
  const size_t pbase = (size_t)b * NCH * DD + d;
  float accA = 0.f;
  for (int cc = 0; cc < c; ++cc) accA += pA[pbase + (size_t)cc * DD];
  float aR = 0.f, aI = 0.f, aM = 0.f;
  const size_t m0 = (size_t)b * SS + (size_t)c * CHS;
  for (int s = 0; s < CHS; ++s) {
    const size_t m = m0 + s;
    const size_t pj = m * NPROJ + d;
    accA = fmaf(__bfloat162float(proj[pj]) * __bfloat162float(proj[pj + DD]), sc, accA);
    float ph = __bfloat162float(phib[m * DD + d]) + accA;
    float cp, sp;
    __sincosf(ph, &sp, &cp);
    float mg = __bfloat162float(proj[pj + 2 * DD]);
    float wc = mg * __bfloat162float(xh[m * DD + d]);
    aR = fmaf(wc, cp, aR);
    aI = fmaf(wc, sp, aI);
    aM += mg;
  }
  size_t pidx = ((size_t)b * NCH + c) * DD + d;
  const size_t stride = (size_t)BSL * NCH * DD;
  pRIM[pidx] = aR;
  pRIM[pidx + stride] = aI;
  pRIM[pidx + 2 * stride] = aM;
}

__global__ __launch_bounds__(512) void scan_final(
    const bf16* __restrict__ proj, const bf16* __restrict__ xh,
    const bf16* __restrict__ phib, const float* __restrict__ iscale,
    const float* __restrict__ pA, const float* __restrict__ pRIM,
    const float* __restrict__ ln_g, const float* __restrict__ ln_b,
    bf16* __restrict__ ctxn)
{
  __shared__ float red[16];
  const int b = blockIdx.x >> 7;
  const int c = blockIdx.x & (NCH - 1);
  const int d = threadIdx.x;
  const float sc = fabsf(iscale[d]);
  const size_t stride = (size_t)BSL * NCH * DD;
  const size_t pbase = (size_t)b * NCH * DD + d;
  // exclusive prefixes (raw partials, ascending order)
  float accA = 0.f, aR = 0.f, aI = 0.f, aM = 0.f;
  for (int cc = 0; cc < c; ++cc) {
    const size_t pi = pbase + (size_t)cc * DD;
    accA += pA[pi];
    aR += pRIM[pi];
    aI += pRIM[pi + stride];
    aM += pRIM[pi + 2 * stride];
  }
  const float g0 = ln_g[d],        e0 = ln_b[d];
  const float g1 = ln_g[DD + d],   e1 = ln_b[DD + d];
  const float g2 = ln_g[2*DD + d], e2 = ln_b[2*DD + d];
  const float g3 = ln_g[3*DD + d], e3 = ln_b[3*DD + d];
  const int lane = threadIdx.x & 63;
  const int wv = threadIdx.x >> 6;
  const size_t m0 = (size_t)b * SS + (size_t)c * CHS;
  for (int s = 0; s < CHS; ++s) {
    const size_t m = m0 + s;
    const size_t pj = m * NPROJ + d;
    // recompute phi (bit-identical to stageB's chain)
    accA = fmaf(__bfloat162float(proj[pj]) * __bfloat162float(proj[pj + DD]), sc, accA);
    float ph = __bfloat162float(phib[m * DD + d]) + accA;
    float xv = __bfloat162float(xh[m * DD + d]);
    float mg = __bfloat162float(proj[pj + 2 * DD]);
    float cp, sp;
    __sincosf(ph, &sp, &cp);
    float wc = mg * xv;
    aR = fmaf(wc, cp, aR);
    aI = fmaf(wc, sp, aI);
    aM += mg;
    float inv = 1.f / sqrtf(aM + 1e-8f);
    float mr = aR * inv, mi = aI * inv;
    float pq = ph + __bfloat162float(proj[pj + 4 * DD]);
    float cq, sq;
    __sincosf(pq, &sq, &cq);
    float rr = fmaf(mr, cq, mi * sq);
    float ri = fmaf(mi, cq, -(mr * sq));
    float v0 = xv * cp, v1 = xv * sp;
    float lsum = (v0 + v1) + (rr + ri);
    float lsq  = fmaf(v0, v0, fmaf(v1, v1, fmaf(rr, rr, ri * ri)));
#pragma unroll
    for (int o = 32; o > 0; o >>= 1) {
      lsum += __shfl_down(lsum, o);
      lsq  += __shfl_down(lsq, o);
    }
    if (lane == 0) { red[wv] = lsum; red[8 + wv] = lsq; }
    __syncthreads();
    float tsum = red[0] + red[1] + red[2] + red[3] + red[4] + red[5] + red[6] + red[7];
    float tsq  = red[8] + red[9] + red[10] + red[11] + red[12] + red[13] + red[14] + red[15];
    __syncthreads();
    const float invN = 1.f / 2048.f;
    float mean = tsum * invN;
    float var  = tsq * invN - mean * mean;
    float rstd = rsqrtf(var + 1e-5f);
    size_t row = m * (4 * DD);
    ctxn[row + d]        = __float2bfloat16(fmaf((v0 - mean) * rstd, g0, e0));
    ctxn[row + DD + d]   = __float2bfloat16(fmaf((v1 - mean) * rstd, g1, e1));
    ctxn[row + 2*DD + d] = __float2bfloat16(fmaf((rr - mean) * rstd, g2, e2));
    ctxn[row + 3*DD + d] = __float2bfloat16(fmaf((ri - mean) * rstd, g3, e3));
  }
}

// ---------------------------------------------------------------------------
extern "C" void kernel_launch(void* const* d_in, const int* in_sizes, int n_in,
                              void* d_out, int out_size, void* d_ws, size_t ws_size,
                              hipStream_t stream)
{
  const float* x       = (const float*)d_in[0];
  const float* W_omega = (const float*)d_in[1];
  const float* b_omega = (const float*)d_in[2];
  const float* W_p1    = (const float*)d_in[3];
  const float* b_p1    = (const float*)d_in[4];
  const float* W_p2    = (const float*)d_in[5];
  const float* b_p2    = (const float*)d_in[6];
  const float* W_gate  = (const float*)d_in[7];
  const float* b_gate  = (const float*)d_in[8];
  const float* iscale  = (const float*)d_in[9];
  const float* W_mag   = (const float*)d_in[10];
  const float* b_mag   = (const float*)d_in[11];
  const float* W_qoff  = (const float*)d_in[12];
  const float* b_qoff  = (const float*)d_in[13];
  const float* ln_g    = (const float*)d_in[14];
  const float* ln_b    = (const float*)d_in[15];
  const float* W_o1    = (const float*)d_in[16];
  const float* b_o1    = (const float*)d_in[17];
  const float* W_o2    = (const float*)d_in[18];
  const float* b_o2    = (const float*)d_in[19];
  float* out = (float*)d_out;

  // Workspace (~102 MB). Es = BSL*SS*DD = 4.19M; Ms = 8192 rows/slice.
  const size_t Es = (size_t)BSL * SS * DD;
  const size_t Ms = (size_t)BSL * SS;
  char* p = (char*)d_ws;
  bf16* proj  = (bf16*)p; p += Ms * NPROJ * 2;            // 41.9 MB
  bf16* phib  = (bf16*)p; p += Es * 2;                    //  8.4 MB
  bf16* xh    = (bf16*)p; p += Es * 2;                    //  8.4 MB
  bf16* ctxn  = (bf16*)p; p += 4 * Es * 2;                // 33.5 MB
  float* pA   = (float*)p; p += (size_t)BSL * NCH * DD * 4;
  float* pRIM = (float*)p; p += 3 * (size_t)BSL * NCH * DD * 4;
  float* bcat = (float*)p; p += NPROJ * 4;
  bf16* WTcat = (bf16*)p; p += (size_t)NPROJ * DD * 2;    //  2.6 MB
  bf16* WTp2  = (bf16*)p; p += (size_t)DD * DD * 2;
  bf16* WTo1  = (bf16*)p; p += (size_t)2048 * 1024 * 2;   //  4.2 MB
  bf16* WTo2  = (bf16*)p; p += (size_t)1024 * 512 * 2;
  bf16* hh    = proj;                                     // [8192,1024] overlay

  dim3 tb(256);
  const size_t WD = (size_t)DD * DD;
  wtrans<<<dim3(16, 16), tb, 0, stream>>>(W_omega, WTcat,          DD, DD);
  wtrans<<<dim3(16, 16), tb, 0, stream>>>(W_gate,  WTcat + WD,     DD, DD);
  wtrans<<<dim3(16, 16), tb, 0, stream>>>(W_mag,   WTcat + 2 * WD, DD, DD);
  wtrans<<<dim3(16, 16), tb, 0, stream>>>(W_p1,    WTcat + 3 * WD, DD, DD);
  wtrans<<<dim3(16, 16), tb, 0, stream>>>(W_qoff,  WTcat + 4 * WD, DD, DD);
  wtrans<<<dim3(16, 16), tb, 0, stream>>>(W_p2,    WTp2, DD, DD);
  wtrans<<<dim3(32, 64), tb, 0, stream>>>(W_o1,    WTo1, 4 * DD, 2 * DD);
  wtrans<<<dim3(16, 32), tb, 0, stream>>>(W_o2,    WTo2, 2 * DD, DD);
  bconcat<<<5, DD, 0, stream>>>(b_omega, b_gate, b_mag, b_p1, b_qoff, bcat);

  const dim3 gP(NPROJ / 128, Ms / 128);        // (20,64)
  const dim3 gD(DD / 128, Ms / 128);           // (4,64)
  const dim3 gO1((2 * DD) / 128, Ms / 128);    // (8,64)

  for (int sl = 0; sl < NSL; ++sl) {
    const float* xs = x + sl * Es;
    float* outs = out + sl * Es;
    castbf<<<(int)(Es / 1024), tb, 0, stream>>>(xs, xh, (int)Es);
    // fused projections + p2
    gemm_mfma<<<gP, tb, 0, stream>>>(xh, DD, WTcat, bcat, nullptr, proj, DD, NPROJ, 9, 1);
    gemm_mfma<<<gD, tb, 0, stream>>>(proj + 3 * DD, NPROJ, WTp2, b_p2, nullptr, phib, DD, DD, 0, 1);
    // scans (partials raw; prefixes summed in consumers)
    scan_partialA<<<BSL * NCH, 512, 0, stream>>>(proj, iscale, pA);
    scan_stageB<<<BSL * NCH, 512, 0, stream>>>(proj, xh, phib, iscale, pA, pRIM);
    scan_final<<<BSL * NCH, 512, 0, stream>>>(proj, xh, phib, iscale, pA, pRIM, ln_g, ln_b, ctxn);
    // output MLP
    gemm_mfma<<<gO1, tb, 0, stream>>>(ctxn, 4 * DD, WTo1, b_o1, nullptr, hh, 4 * DD, 2 * DD, 3, 1);
    gemm_mfma<<<gD, tb, 0, stream>>>(hh, 2 * DD, WTo2, b_o2, xs, outs, 2 * DD, DD, 0, 0);
  }
}

// Round 6
// 1399.966 us; speedup vs baseline: 1.1106x; 1.1106x over previous
//
#include <hip/hip_runtime.h>
#include <hip/hip_bf16.h>
#include <math.h>

// PSI_Full: B=8, S=4096, D=512. fp32 in/out.
// Round 6: (1) scans reverted to the round-4 structure (phi fp32 buffer +
// scan_excl kernels) — round-5's in-kernel prefixes/recompute measured ~+43
// us/slice. (2) GEMM BK 32->64: 32 MFMAs between barriers (AITER-style),
// half the barrier drains; LDS 32KB still fits the grid-capped 2 blocks/CU.
// XCD swizzle kept (o1 FETCH 133->33 MB, measured round 5).

#define BB 8
#define SS 4096
#define DD 512
#define NCH 128
#define CHS 32        // SS / NCH
#define BSL 2         // batch per slice
#define NSL 4
#define NPROJ 2560    // 5 * DD

typedef __attribute__((ext_vector_type(8))) short short8;
typedef __attribute__((ext_vector_type(4))) float f32x4;
typedef __hip_bfloat16 bf16;

__device__ inline void load_lds16(const bf16* g, bf16* l) {
  __builtin_amdgcn_global_load_lds(
      (const __attribute__((address_space(1))) void*)g,
      (__attribute__((address_space(3))) void*)l, 16, 0, 0);
}

// ---------------------------------------------------------------------------
// bf16 MFMA GEMM: C[M,N] = act(A[M,K](lda=Alda) @ WT[N,K]^T + bias[N]) (+resid)
// act: 0 none, 1 sig, 2 sig*5, 3 gelu(exact), 9 = fused-proj table by col>>9.
// Tile 128x128, BK=64, 256 threads = 4 waves (2x2), each wave 4x4 of 16x16.
// K multiple of 64. XCD swizzle (gy==64): XCD c8 gets row band 8*c8..8*c8+7.
// ---------------------------------------------------------------------------
__global__ __launch_bounds__(256) void gemm_mfma(
    const bf16* __restrict__ A, int Alda,
    const bf16* __restrict__ WT,            // [N][K]
    const float* __restrict__ bias,
    const float* __restrict__ resid,        // fp32 [M][N] or null
    void* __restrict__ C, int K, int N, int act, int outBf16)
{
  __shared__ bf16 As[8192];  // [kseg 0..7][row 0..127][8]
  __shared__ bf16 Bs[8192];
  const int tid = threadIdx.x;
  int bx, by;
  if (gridDim.y == 64) {
    const int l = blockIdx.y * gridDim.x + blockIdx.x;
    const int c8 = l & 7, i = l >> 3;
    by = (c8 << 3) + (i & 7);     // row-block: XCD-contiguous band
    bx = i >> 3;                  // col-block
  } else { bx = blockIdx.x; by = blockIdx.y; }
  const int row0 = by << 7;
  const int col0 = bx << 7;
  const int lane = tid & 63;
  const int wv = tid >> 6;
  const int wr = (wv >> 1) << 6;
  const int wc = (wv & 1) << 6;
  const int q  = lane >> 4;
  const int mn = lane & 15;

  int eact = act;
  if (act == 9) { const int tbl[5] = {0, 1, 2, 3, 0}; eact = tbl[col0 >> 9]; }

  f32x4 acc[4][4];
#pragma unroll
  for (int i = 0; i < 4; ++i)
#pragma unroll
    for (int j = 0; j < 4; ++j) acc[i][j] = (f32x4){0.f, 0.f, 0.f, 0.f};

  const int srow = tid & 127;
  const bf16* Ag = A  + (size_t)(row0 + srow) * Alda + ((tid >> 7) << 3);
  const bf16* Bg = WT + (size_t)(col0 + srow) * K + ((tid >> 7) << 3);
  bf16* Asl = As + tid * 8;
  bf16* Bsl = Bs + tid * 8;

  for (int k0 = 0; k0 < K; k0 += 64) {
    __syncthreads();
#pragma unroll
    for (int i = 0; i < 4; ++i) {
      load_lds16(Ag + k0 + i * 16, Asl + i * 2048);
      load_lds16(Bg + k0 + i * 16, Bsl + i * 2048);
    }
    __syncthreads();
    const short8* Av = (const short8*)As;   // index = kseg*128 + row
    const short8* Bv = (const short8*)Bs;
#pragma unroll
    for (int j = 0; j < 2; ++j) {           // two K=32 sub-steps
      short8 af[4], bfr[4];
      const int ks = (j << 2) + q;
#pragma unroll
      for (int t = 0; t < 4; ++t) af[t]  = Av[ks * 128 + wr + t * 16 + mn];
#pragma unroll
      for (int t = 0; t < 4; ++t) bfr[t] = Bv[ks * 128 + wc + t * 16 + mn];
#pragma unroll
      for (int mt = 0; mt < 4; ++mt)
#pragma unroll
        for (int nt = 0; nt < 4; ++nt)
          acc[mt][nt] = __builtin_amdgcn_mfma_f32_16x16x32_bf16(
              af[mt], bfr[nt], acc[mt][nt], 0, 0, 0);
    }
  }

  // C/D layout: col = lane&15, row = quad*4 + reg.
#pragma unroll
  for (int mt = 0; mt < 4; ++mt) {
#pragma unroll
    for (int nt = 0; nt < 4; ++nt) {
      const int gcol = col0 + wc + nt * 16 + mn;
      const float bcol = bias[gcol];
#pragma unroll
      for (int r = 0; r < 4; ++r) {
        const int grow = row0 + wr + mt * 16 + q * 4 + r;
        const size_t o = (size_t)grow * N + gcol;
        float v = acc[mt][nt][r] + bcol;
        if (eact == 1)      v = 1.f / (1.f + __expf(-v));
        else if (eact == 2) v = 5.f / (1.f + __expf(-v));
        else if (eact == 3) v = 0.5f * v * (1.f + erff(v * 0.70710678118654752f));
        if (resid) v += resid[o];
        if (outBf16) ((bf16*)C)[o] = __float2bfloat16(v);
        else         ((float*)C)[o] = v;
      }
    }
  }
}

// ---------------------------------------------------------------------------
__global__ __launch_bounds__(256) void wtrans(
    const float* __restrict__ W, bf16* __restrict__ WT, int K, int N)
{
  __shared__ float t[32][33];
  const int n0 = blockIdx.x << 5, k0 = blockIdx.y << 5;
  const int tx = threadIdx.x & 31, ty = threadIdx.x >> 5;
  for (int i = ty; i < 32; i += 8)
    t[i][tx] = W[(size_t)(k0 + i) * N + n0 + tx];
  __syncthreads();
  for (int i = ty; i < 32; i += 8)
    WT[(size_t)(n0 + i) * K + k0 + tx] = __float2bfloat16(t[tx][i]);
}

__global__ __launch_bounds__(256) void castbf(
    const float* __restrict__ in, bf16* __restrict__ o, int n)
{
  const int i = (blockIdx.x * 256 + threadIdx.x) * 4;
  if (i < n) {
    const float4 v = *(const float4*)(in + i);
    o[i]     = __float2bfloat16(v.x);
    o[i + 1] = __float2bfloat16(v.y);
    o[i + 2] = __float2bfloat16(v.z);
    o[i + 3] = __float2bfloat16(v.w);
  }
}

// bias concat: 5 segments of 512 -> bcat[2560]
__global__ void bconcat(const float* b0, const float* b1, const float* b2,
                        const float* b3, const float* b4, float* bcat)
{
  const int d = threadIdx.x;
  const float* src[5] = {b0, b1, b2, b3, b4};
  bcat[blockIdx.x * DD + d] = src[blockIdx.x][d];
}

// ---------------------------------------------------------------------------
// Scans (round-4 structure). proj row m: [omega|gate|mag|g1|qoff] bf16,
// stride NPROJ. phi_init in phib (bf16); running phi fp32 buffer.
// ---------------------------------------------------------------------------
__global__ __launch_bounds__(512) void scan_partialA(
    const bf16* __restrict__ proj, const float* __restrict__ iscale,
    float* __restrict__ pA)
{
  const int b = blockIdx.x >> 7;
  const int c = blockIdx.x & (NCH - 1);
  const int d = threadIdx.x;
  const float sc = fabsf(iscale[d]);
  size_t base = (((size_t)b * SS) + (size_t)c * CHS) * NPROJ + d;
  float acc = 0.f;
  for (int s = 0; s < CHS; ++s) {
    size_t idx = base + (size_t)s * NPROJ;
    acc = fmaf(__bfloat162float(proj[idx]) * __bfloat162float(proj[idx + DD]), sc, acc);
  }
  pA[((size_t)b * NCH + c) * DD + d] = acc;
}

__global__ void scan_excl(float* __restrict__ p, int batch)
{
  int t = blockIdx.x * 256 + threadIdx.x;
  if (t >= batch * DD) return;
  int g = t / DD, d = t % DD;
  size_t base = (size_t)g * NCH * DD + d;
  float run = 0.f;
  for (int c = 0; c < NCH; ++c) {
    size_t idx = base + (size_t)c * DD;
    float v = p[idx];
    p[idx] = run;
    run += v;
  }
}

__global__ __launch_bounds__(512) void scan_stageB(
    const bf16* __restrict__ proj, const bf16* __restrict__ xh,
    const bf16* __restrict__ phib, const float* __restrict__ iscale,
    float* __restrict__ phi, const float* __restrict__ pA,
    float* __restrict__ pRIM)
{
  const int b = blockIdx.x >> 7;
  const int c = blockIdx.x & (NCH - 1);
  const int d = threadIdx.x;
  const float sc = fabsf(iscale[d]);
  float accA = pA[((size_t)b * NCH + c) * DD + d];
  float aR = 0.f, aI = 0.f, aM = 0.f;
  const size_t m0 = (size_t)b * SS + (size_t)c * CHS;
  for (int s = 0; s < CHS; ++s) {
    const size_t m = m0 + s;
    const size_t pj = m * NPROJ + d;
    accA = fmaf(__bfloat162float(proj[pj]) * __bfloat162float(proj[pj + DD]), sc, accA);
    float ph = __bfloat162float(phib[m * DD + d]) + accA;
    phi[m * DD + d] = ph;
    float cp, sp;
    __sincosf(ph, &sp, &cp);
    float mg = __bfloat162float(proj[pj + 2 * DD]);
    float wc = mg * __bfloat162float(xh[m * DD + d]);
    aR = fmaf(wc, cp, aR);
    aI = fmaf(wc, sp, aI);
    aM += mg;
  }
  size_t pidx = ((size_t)b * NCH + c) * DD + d;
  const size_t stride = (size_t)BSL * NCH * DD;
  pRIM[pidx] = aR;
  pRIM[pidx + stride] = aI;
  pRIM[pidx + 2 * stride] = aM;
}

__global__ __launch_bounds__(512) void scan_final(
    const bf16* __restrict__ proj, const bf16* __restrict__ xh,
    const float* __restrict__ phi, const float* __restrict__ pRIM,
    const float* __restrict__ ln_g, const float* __restrict__ ln_b,
    bf16* __restrict__ ctxn)
{
  __shared__ float red[16];
  const int b = blockIdx.x >> 7;
  const int c = blockIdx.x & (NCH - 1);
  const int d = threadIdx.x;
  size_t pidx = ((size_t)b * NCH + c) * DD + d;
  const size_t stride = (size_t)BSL * NCH * DD;
  float aR = pRIM[pidx];
  float aI = pRIM[pidx + stride];
  float aM = pRIM[pidx + 2 * stride];
  const float g0 = ln_g[d],        e0 = ln_b[d];
  const float g1 = ln_g[DD + d],   e1 = ln_b[DD + d];
  const float g2 = ln_g[2*DD + d], e2 = ln_b[2*DD + d];
  const float g3 = ln_g[3*DD + d], e3 = ln_b[3*DD + d];
  const int lane = threadIdx.x & 63;
  const int wv = threadIdx.x >> 6;
  const size_t m0 = (size_t)b * SS + (size_t)c * CHS;
  for (int s = 0; s < CHS; ++s) {
    const size_t m = m0 + s;
    const size_t pj = m * NPROJ + d;
    float ph = phi[m * DD + d];
    float xv = __bfloat162float(xh[m * DD + d]);
    float mg = __bfloat162float(proj[pj + 2 * DD]);
    float cp, sp;
    __sincosf(ph, &sp, &cp);
    float wc = mg * xv;
    aR = fmaf(wc, cp, aR);
    aI = fmaf(wc, sp, aI);
    aM += mg;
    float inv = 1.f / sqrtf(aM + 1e-8f);
    float mr = aR * inv, mi = aI * inv;
    float pq = ph + __bfloat162float(proj[pj + 4 * DD]);
    float cq, sq;
    __sincosf(pq, &sq, &cq);
    float rr = fmaf(mr, cq, mi * sq);
    float ri = fmaf(mi, cq, -(mr * sq));
    float v0 = xv * cp, v1 = xv * sp;
    float lsum = (v0 + v1) + (rr + ri);
    float lsq  = fmaf(v0, v0, fmaf(v1, v1, fmaf(rr, rr, ri * ri)));
#pragma unroll
    for (int o = 32; o > 0; o >>= 1) {
      lsum += __shfl_down(lsum, o);
      lsq  += __shfl_down(lsq, o);
    }
    if (lane == 0) { red[wv] = lsum; red[8 + wv] = lsq; }
    __syncthreads();
    float tsum = red[0] + red[1] + red[2] + red[3] + red[4] + red[5] + red[6] + red[7];
    float tsq  = red[8] + red[9] + red[10] + red[11] + red[12] + red[13] + red[14] + red[15];
    __syncthreads();
    const float invN = 1.f / 2048.f;
    float mean = tsum * invN;
    float var  = tsq * invN - mean * mean;
    float rstd = rsqrtf(var + 1e-5f);
    size_t row = m * (4 * DD);
    ctxn[row + d]        = __float2bfloat16(fmaf((v0 - mean) * rstd, g0, e0));
    ctxn[row + DD + d]   = __float2bfloat16(fmaf((v1 - mean) * rstd, g1, e1));
    ctxn[row + 2*DD + d] = __float2bfloat16(fmaf((rr - mean) * rstd, g2, e2));
    ctxn[row + 3*DD + d] = __float2bfloat16(fmaf((ri - mean) * rstd, g3, e3));
  }
}

// ---------------------------------------------------------------------------
extern "C" void kernel_launch(void* const* d_in, const int* in_sizes, int n_in,
                              void* d_out, int out_size, void* d_ws, size_t ws_size,
                              hipStream_t stream)
{
  const float* x       = (const float*)d_in[0];
  const float* W_omega = (const float*)d_in[1];
  const float* b_omega = (const float*)d_in[2];
  const float* W_p1    = (const float*)d_in[3];
  const float* b_p1    = (const float*)d_in[4];
  const float* W_p2    = (const float*)d_in[5];
  const float* b_p2    = (const float*)d_in[6];
  const float* W_gate  = (const float*)d_in[7];
  const float* b_gate  = (const float*)d_in[8];
  const float* iscale  = (const float*)d_in[9];
  const float* W_mag   = (const float*)d_in[10];
  const float* b_mag   = (const float*)d_in[11];
  const float* W_qoff  = (const float*)d_in[12];
  const float* b_qoff  = (const float*)d_in[13];
  const float* ln_g    = (const float*)d_in[14];
  const float* ln_b    = (const float*)d_in[15];
  const float* W_o1    = (const float*)d_in[16];
  const float* b_o1    = (const float*)d_in[17];
  const float* W_o2    = (const float*)d_in[18];
  const float* b_o2    = (const float*)d_in[19];
  float* out = (float*)d_out;

  // Workspace (~119 MB). Es = BSL*SS*DD = 4.19M; Ms = 8192 rows/slice.
  const size_t Es = (size_t)BSL * SS * DD;
  const size_t Ms = (size_t)BSL * SS;
  char* p = (char*)d_ws;
  bf16* proj  = (bf16*)p; p += Ms * NPROJ * 2;            // 41.9 MB
  bf16* phib  = (bf16*)p; p += Es * 2;                    //  8.4 MB
  float* phi  = (float*)p; p += Es * 4;                   // 16.8 MB
  bf16* xh    = (bf16*)p; p += Es * 2;                    //  8.4 MB
  bf16* ctxn  = (bf16*)p; p += 4 * Es * 2;                // 33.5 MB
  float* pA   = (float*)p; p += (size_t)BSL * NCH * DD * 4;
  float* pRIM = (float*)p; p += 3 * (size_t)BSL * NCH * DD * 4;
  float* bcat = (float*)p; p += NPROJ * 4;
  bf16* WTcat = (bf16*)p; p += (size_t)NPROJ * DD * 2;    //  2.6 MB
  bf16* WTp2  = (bf16*)p; p += (size_t)DD * DD * 2;
  bf16* WTo1  = (bf16*)p; p += (size_t)2048 * 1024 * 2;   //  4.2 MB
  bf16* WTo2  = (bf16*)p; p += (size_t)1024 * 512 * 2;
  bf16* hh    = proj;                                     // [8192,1024] overlay

  dim3 tb(256);
  const size_t WD = (size_t)DD * DD;
  wtrans<<<dim3(16, 16), tb, 0, stream>>>(W_omega, WTcat,          DD, DD);
  wtrans<<<dim3(16, 16), tb, 0, stream>>>(W_gate,  WTcat + WD,     DD, DD);
  wtrans<<<dim3(16, 16), tb, 0, stream>>>(W_mag,   WTcat + 2 * WD, DD, DD);
  wtrans<<<dim3(16, 16), tb, 0, stream>>>(W_p1,    WTcat + 3 * WD, DD, DD);
  wtrans<<<dim3(16, 16), tb, 0, stream>>>(W_qoff,  WTcat + 4 * WD, DD, DD);
  wtrans<<<dim3(16, 16), tb, 0, stream>>>(W_p2,    WTp2, DD, DD);
  wtrans<<<dim3(32, 64), tb, 0, stream>>>(W_o1,    WTo1, 4 * DD, 2 * DD);
  wtrans<<<dim3(16, 32), tb, 0, stream>>>(W_o2,    WTo2, 2 * DD, DD);
  bconcat<<<5, DD, 0, stream>>>(b_omega, b_gate, b_mag, b_p1, b_qoff, bcat);

  const dim3 gP(NPROJ / 128, Ms / 128);        // (20,64)
  const dim3 gD(DD / 128, Ms / 128);           // (4,64)
  const dim3 gO1((2 * DD) / 128, Ms / 128);    // (8,64)

  for (int sl = 0; sl < NSL; ++sl) {
    const float* xs = x + sl * Es;
    float* outs = out + sl * Es;
    castbf<<<(int)(Es / 1024), tb, 0, stream>>>(xs, xh, (int)Es);
    // fused projections + p2
    gemm_mfma<<<gP, tb, 0, stream>>>(xh, DD, WTcat, bcat, nullptr, proj, DD, NPROJ, 9, 1);
    gemm_mfma<<<gD, tb, 0, stream>>>(proj + 3 * DD, NPROJ, WTp2, b_p2, nullptr, phib, DD, DD, 0, 1);
    // scans
    scan_partialA<<<BSL * NCH, 512, 0, stream>>>(proj, iscale, pA);
    scan_excl<<<(BSL * DD + 255) / 256, 256, 0, stream>>>(pA, BSL);
    scan_stageB<<<BSL * NCH, 512, 0, stream>>>(proj, xh, phib, iscale, phi, pA, pRIM);
    scan_excl<<<(3 * BSL * DD + 255) / 256, 256, 0, stream>>>(pRIM, 3 * BSL);
    scan_final<<<BSL * NCH, 512, 0, stream>>>(proj, xh, phi, pRIM, ln_g, ln_b, ctxn);
    // output MLP
    gemm_mfma<<<gO1, tb, 0, stream>>>(ctxn, 4 * DD, WTo1, b_o1, nullptr, hh, 4 * DD, 2 * DD, 3, 1);
    gemm_mfma<<<gD, tb, 0, stream>>>(hh, 2 * DD, WTo2, b_o2, xs, outs, 2 * DD, DD, 0, 0);
  }
}